// Round 1
// baseline (2377.440 us; speedup 1.0000x reference)
//
#include <hip/hip_runtime.h>
#include <stdint.h>
#include <stddef.h>

typedef float f32x4 __attribute__((ext_vector_type(4)));

// ---------------------------------------------------------------------------
// Workspace layout (bytes):
//   [0..7]    : two u32 atomic absmax slots (w_absmax_bits, x_absmax_bits)
//   [8..255]  : scales as float: idx2=1/w_scale, idx3=1/x_scale, idx4=w_scale*x_scale
//   [256 .. 256+M*K)            : x_q  fp8 [M][K]   (32 MB)
//   [256+M*K .. 256+M*K+N*K)    : w_qT fp8 [N][K]   (64 MB)
// Total ~96 MB.
// ---------------------------------------------------------------------------

__global__ void absmax_kernel(const float4* __restrict__ x, size_t n4,
                              unsigned int* __restrict__ out) {
  size_t idx = (size_t)blockIdx.x * blockDim.x + threadIdx.x;
  size_t stride = (size_t)gridDim.x * blockDim.x;
  float m = 0.f;
  for (size_t i = idx; i < n4; i += stride) {
    float4 v = x[i];
    m = fmaxf(m, fmaxf(fmaxf(fabsf(v.x), fabsf(v.y)),
                       fmaxf(fabsf(v.z), fabsf(v.w))));
  }
#pragma unroll
  for (int off = 32; off > 0; off >>= 1)
    m = fmaxf(m, __shfl_xor(m, off));
  if ((threadIdx.x & 63) == 0)
    atomicMax(out, __float_as_uint(m));  // all values >= 0: uint order == float order
}

__global__ void scales_kernel(float* __restrict__ s) {
  const unsigned int* u = (const unsigned int*)s;
  float wmax = __uint_as_float(u[0]);
  float xmax = __uint_as_float(u[1]);
  float w_scale = wmax / 448.0f;   // exactly as reference: amax / F8_MAX
  float x_scale = xmax / 448.0f;
  s[2] = 1.0f / w_scale;           // reference multiplies by (1.0/scale)
  s[3] = 1.0f / x_scale;
  s[4] = x_scale * w_scale;
}

// x: [M*K] f32 -> xq fp8 (same layout). One float4 -> one packed u32 per iter.
__global__ void quantize_x_kernel(const float4* __restrict__ x,
                                  uint32_t* __restrict__ xq,
                                  const float* __restrict__ scales, int n4) {
  float inv = scales[3];
  int idx = blockIdx.x * blockDim.x + threadIdx.x;
  int stride = gridDim.x * blockDim.x;
  for (int i = idx; i < n4; i += stride) {
    float4 v = x[i];
    int lo = __builtin_amdgcn_cvt_pk_fp8_f32(v.x * inv, v.y * inv, 0, false);
    int hi = __builtin_amdgcn_cvt_pk_fp8_f32(v.z * inv, v.w * inv, lo, true);
    xq[i] = (uint32_t)hi;
  }
}

// w: [K][N] f32 row-major -> wqt: [N][K] fp8 (transposed), via 64x64 LDS tile.
// grid = (N/64, K/64), block = 256.
__global__ void quantize_wT_kernel(const float* __restrict__ w,
                                   uint8_t* __restrict__ wqt,
                                   const float* __restrict__ scales,
                                   int N, int K) {
  __shared__ uint8_t tile[64][68];  // [k][n], padded row to dodge bank conflicts
  float inv = scales[2];
  int tn = blockIdx.x;  // n tile
  int tk = blockIdx.y;  // k tile
  int t = threadIdx.x;
  int rr = t >> 4;      // 0..15
  int cc4 = t & 15;     // 0..15 (float4 column)
#pragma unroll
  for (int i = 0; i < 4; ++i) {
    int row = rr + i * 16;  // k within tile
    const float4 v = *(const float4*)&w[(size_t)(tk * 64 + row) * N + tn * 64 + cc4 * 4];
    int lo = __builtin_amdgcn_cvt_pk_fp8_f32(v.x * inv, v.y * inv, 0, false);
    int hi = __builtin_amdgcn_cvt_pk_fp8_f32(v.z * inv, v.w * inv, lo, true);
    *(uint32_t*)&tile[row][cc4 * 4] = (uint32_t)hi;
  }
  __syncthreads();
#pragma unroll
  for (int i = 0; i < 4; ++i) {
    int nrow = rr + i * 16;  // n within tile
    int kc = cc4 * 4;        // k within tile
    uint32_t b = (uint32_t)tile[kc][nrow] | ((uint32_t)tile[kc + 1][nrow] << 8) |
                 ((uint32_t)tile[kc + 2][nrow] << 16) | ((uint32_t)tile[kc + 3][nrow] << 24);
    *(uint32_t*)&wqt[(size_t)(tn * 64 + nrow) * K + tk * 64 + kc] = b;
  }
}

// ---------------------------------------------------------------------------
// fp8 GEMM: C[M][N] = (Aq[M][K] . BqT[N][K]^T) * s + bias
// 128x128 tile, BK=64, 4 waves (2x2), 16x16x32 fp8 MFMA, global_load_lds x16.
// ---------------------------------------------------------------------------
#define BM 128
#define BN 128
#define BKQ 64

__device__ __forceinline__ void gl_lds16(const uint8_t* g, uint8_t* lds) {
  __builtin_amdgcn_global_load_lds(
      (const __attribute__((address_space(1))) void*)g,
      (__attribute__((address_space(3))) void*)lds, 16, 0, 0);
}

__global__ __launch_bounds__(256) void gemm_fp8_kernel(
    const uint8_t* __restrict__ Aq, const uint8_t* __restrict__ BqT,
    const float* __restrict__ bias, const float* __restrict__ scales,
    float* __restrict__ C, int M, int N, int K) {
  __shared__ __align__(16) uint8_t As[BM * BKQ];
  __shared__ __align__(16) uint8_t Bs[BN * BKQ];

  // XCD-aware swizzle (nwg = 8192, divisible by 8)
  int nwg = gridDim.x;
  int cpx = nwg >> 3;
  int bid = blockIdx.x;
  int wg = (bid & 7) * cpx + (bid >> 3);
  int ntn = N / BN;
  int tm = wg / ntn;
  int tn = wg % ntn;
  int m0 = tm * BM;
  int n0 = tn * BN;

  const int t = threadIdx.x;
  const int w = t >> 6;        // wave 0..3
  const int l = t & 63;        // lane
  const int wm = w >> 1;       // 0..1 wave row
  const int wn = w & 1;        // 0..1 wave col

  f32x4 acc[4][4] = {};

  // staging address components (constant per thread)
  const int srow = (l >> 2);        // +half*16
  const int scol = (l & 3) * 16;

  const int kt_count = K / BKQ;
  for (int kt = 0; kt < kt_count; ++kt) {
    int k0 = kt * BKQ;
    // stage A and B tiles: 8 KB each, 4 x global_load_lds(16B) per thread
#pragma unroll
    for (int i = 0; i < 2; ++i) {
      int half = i * 4 + w;                       // 0..7, wave-uniform
      int row = half * 16 + srow;                 // 0..127
      gl_lds16(Aq + (size_t)(m0 + row) * K + k0 + scol, As + half * 1024);
      gl_lds16(BqT + (size_t)(n0 + row) * K + k0 + scol, Bs + half * 1024);
    }
    __syncthreads();  // compiler drains vmcnt before barrier

#pragma unroll
    for (int kk = 0; kk < 2; ++kk) {
      long a[4], b[4];
      int fro = (l & 15);          // fragment row within 16
      int fko = kk * 32 + ((l >> 4) * 8);  // k byte offset
#pragma unroll
      for (int m = 0; m < 4; ++m)
        a[m] = *(const long*)(As + (wm * 64 + m * 16 + fro) * BKQ + fko);
#pragma unroll
      for (int n = 0; n < 4; ++n)
        b[n] = *(const long*)(Bs + (wn * 64 + n * 16 + fro) * BKQ + fko);
#pragma unroll
      for (int m = 0; m < 4; ++m)
#pragma unroll
        for (int n = 0; n < 4; ++n)
          acc[m][n] = __builtin_amdgcn_mfma_f32_16x16x32_fp8_fp8(
              a[m], b[n], acc[m][n], 0, 0, 0);
    }
    __syncthreads();  // protect LDS before next stage
  }

  // epilogue: C = acc * (x_scale*w_scale) + bias
  float s = scales[4];
  int crow0 = m0 + wm * 64 + ((l >> 4) * 4);
  int ccol0 = n0 + wn * 64 + (l & 15);
#pragma unroll
  for (int n = 0; n < 4; ++n) {
    int col = ccol0 + n * 16;
    float bv = bias[col];
#pragma unroll
    for (int m = 0; m < 4; ++m) {
      int rowb = crow0 + m * 16;
#pragma unroll
      for (int r = 0; r < 4; ++r) {
        C[(size_t)(rowb + r) * N + col] = acc[m][n][r] * s + bv;
      }
    }
  }
}

extern "C" void kernel_launch(void* const* d_in, const int* in_sizes, int n_in,
                              void* d_out, int out_size, void* d_ws, size_t ws_size,
                              hipStream_t stream) {
  const float* inp = (const float*)d_in[0];
  const float* weight = (const float*)d_in[1];
  const float* bias = (const float*)d_in[2];
  float* out = (float*)d_out;

  const int N = in_sizes[2];                 // 16384
  const int K = in_sizes[1] / N;             // 4096
  const int M = in_sizes[0] / K;             // 8192

  uint8_t* ws = (uint8_t*)d_ws;
  float* scales = (float*)ws;
  uint8_t* xq = ws + 256;
  uint8_t* wqt = ws + 256 + (size_t)M * K;

  // zero the atomic absmax slots (ws is poisoned 0xAA)
  hipMemsetAsync(d_ws, 0, 256, stream);

  absmax_kernel<<<2048, 256, 0, stream>>>((const float4*)weight,
                                          (size_t)K * N / 4,
                                          (unsigned int*)ws + 0);
  absmax_kernel<<<2048, 256, 0, stream>>>((const float4*)inp,
                                          (size_t)M * K / 4,
                                          (unsigned int*)ws + 1);
  scales_kernel<<<1, 1, 0, stream>>>(scales);

  quantize_x_kernel<<<4096, 256, 0, stream>>>((const float4*)inp,
                                              (uint32_t*)xq, scales, M * K / 4);
  quantize_wT_kernel<<<dim3(N / 64, K / 64), 256, 0, stream>>>(weight, wqt,
                                                               scales, N, K);

  gemm_fp8_kernel<<<(M / BM) * (N / BN), 256, 0, stream>>>(
      xq, wqt, bias, scales, out, M, N, K);
}

// Round 2
// 1482.108 us; speedup vs baseline: 1.6041x; 1.6041x over previous
//
#include <hip/hip_runtime.h>
#include <stdint.h>
#include <stddef.h>

typedef float f32x4 __attribute__((ext_vector_type(4)));

// ---------------------------------------------------------------------------
// Workspace layout (bytes):
//   [0..7]    : two u32 atomic absmax slots (w_absmax_bits, x_absmax_bits)
//   [8..255]  : scales as float: idx2=1/w_scale, idx3=1/x_scale, idx4=w_scale*x_scale
//   [256 .. 256+M*K)            : x_q  fp8 [M][K]   (32 MB)
//   [256+M*K .. 256+M*K+N*K)    : w_qT fp8 [N][K]   (64 MB)
// ---------------------------------------------------------------------------

__global__ void absmax_kernel(const float4* __restrict__ x, size_t n4,
                              unsigned int* __restrict__ out) {
  size_t idx = (size_t)blockIdx.x * blockDim.x + threadIdx.x;
  size_t stride = (size_t)gridDim.x * blockDim.x;
  float m = 0.f;
  for (size_t i = idx; i < n4; i += stride) {
    float4 v = x[i];
    m = fmaxf(m, fmaxf(fmaxf(fabsf(v.x), fabsf(v.y)),
                       fmaxf(fabsf(v.z), fabsf(v.w))));
  }
#pragma unroll
  for (int off = 32; off > 0; off >>= 1)
    m = fmaxf(m, __shfl_xor(m, off));
  if ((threadIdx.x & 63) == 0)
    atomicMax(out, __float_as_uint(m));  // all values >= 0: uint order == float order
}

__global__ void scales_kernel(float* __restrict__ s) {
  const unsigned int* u = (const unsigned int*)s;
  float wmax = __uint_as_float(u[0]);
  float xmax = __uint_as_float(u[1]);
  float w_scale = wmax / 448.0f;
  float x_scale = xmax / 448.0f;
  s[2] = 1.0f / w_scale;
  s[3] = 1.0f / x_scale;
  s[4] = x_scale * w_scale;
}

__global__ void quantize_x_kernel(const float4* __restrict__ x,
                                  uint32_t* __restrict__ xq,
                                  const float* __restrict__ scales, int n4) {
  float inv = scales[3];
  int idx = blockIdx.x * blockDim.x + threadIdx.x;
  int stride = gridDim.x * blockDim.x;
  for (int i = idx; i < n4; i += stride) {
    float4 v = x[i];
    int lo = __builtin_amdgcn_cvt_pk_fp8_f32(v.x * inv, v.y * inv, 0, false);
    int hi = __builtin_amdgcn_cvt_pk_fp8_f32(v.z * inv, v.w * inv, lo, true);
    xq[i] = (uint32_t)hi;
  }
}

// w: [K][N] f32 row-major -> wqt: [N][K] fp8 (transposed), via 64x64 LDS tile.
__global__ void quantize_wT_kernel(const float* __restrict__ w,
                                   uint8_t* __restrict__ wqt,
                                   const float* __restrict__ scales,
                                   int N, int K) {
  __shared__ uint8_t tile[64][68];
  float inv = scales[2];
  int tn = blockIdx.x;
  int tk = blockIdx.y;
  int t = threadIdx.x;
  int rr = t >> 4;
  int cc4 = t & 15;
#pragma unroll
  for (int i = 0; i < 4; ++i) {
    int row = rr + i * 16;
    const float4 v = *(const float4*)&w[(size_t)(tk * 64 + row) * N + tn * 64 + cc4 * 4];
    int lo = __builtin_amdgcn_cvt_pk_fp8_f32(v.x * inv, v.y * inv, 0, false);
    int hi = __builtin_amdgcn_cvt_pk_fp8_f32(v.z * inv, v.w * inv, lo, true);
    *(uint32_t*)&tile[row][cc4 * 4] = (uint32_t)hi;
  }
  __syncthreads();
#pragma unroll
  for (int i = 0; i < 4; ++i) {
    int nrow = rr + i * 16;
    int kc = cc4 * 4;
    uint32_t b = (uint32_t)tile[kc][nrow] | ((uint32_t)tile[kc + 1][nrow] << 8) |
                 ((uint32_t)tile[kc + 2][nrow] << 16) | ((uint32_t)tile[kc + 3][nrow] << 24);
    *(uint32_t*)&wqt[(size_t)(tn * 64 + nrow) * K + tk * 64 + kc] = b;
  }
}

// ---------------------------------------------------------------------------
// fp8 GEMM, 256x256 tile, 8-phase ring schedule (T3+T4+T5).
//   - 8 waves (2 Mx4 N), per-wave out 128x64, 16x16x32 fp8 MFMA.
//   - K-tile BK=128 split into 4 K=32 slices; LDS = 8-slot ring per operand,
//     slot = 8KB slice [kp(16B k-chunk)][256 rows][16B] -> ds_read_b64 frag
//     reads hit 4 accesses/bank (the b64 floor): conflict-free, no swizzle,
//     and staging stays linear so global_load_lds width-16 applies.
//   - Each phase stages slice g+4 (ring lead 4), counted vmcnt(6), raw
//     s_barrier, lgkmcnt(0), setprio(1) around 32 MFMA.
// ---------------------------------------------------------------------------
#define T_BM 256
#define T_BN 256
#define T_BK 128

__device__ __forceinline__ void gl_lds16(const uint8_t* g, uint8_t* lds) {
  __builtin_amdgcn_global_load_lds(
      (const __attribute__((address_space(1))) void*)g,
      (__attribute__((address_space(3))) void*)lds, 16, 0, 0);
}

__global__ __launch_bounds__(512, 2) void gemm_fp8_8phase(
    const uint8_t* __restrict__ Aq, const uint8_t* __restrict__ BqT,
    const float* __restrict__ bias, const float* __restrict__ scales,
    float* __restrict__ C, int M, int N, int K) {
  extern __shared__ uint8_t smem[];
  uint8_t* const Ab = smem;            // 8 slots x 8192 = 64 KB
  uint8_t* const Bb = smem + 65536;    // 8 slots x 8192 = 64 KB

  const int ntn = N / T_BN;
  const int bid = blockIdx.x;
  const int m0 = (bid / ntn) * T_BM;
  const int n0 = (bid % ntn) * T_BN;

  const int tid = threadIdx.x;
  const int w = tid >> 6;      // wave 0..7
  const int l = tid & 63;
  const int wr = w >> 2;       // 0..1  (M half)
  const int wc = w & 3;        // 0..3  (N quarter)

  // staging constants: wave w stages rows (w&3)*64+l of the slice at k-chunk kp=w>>2
  const int srow = (w & 3) * 64 + l;
  const int skp = (w >> 2) * 16;
  const uint8_t* a_src = Aq + (size_t)(m0 + srow) * K + skp;
  const uint8_t* b_src = BqT + (size_t)(n0 + srow) * K + skp;
  const int soff = w * 1024;   // wave-uniform LDS offset within slot

  // fragment-read constants: lane l reads logical k-bytes [kg*8, kg*8+8)
  const int fro = l & 15;
  const int kg = l >> 4;
  const int a_off = (kg >> 1) * 4096 + (wr * 128 + fro) * 16 + (kg & 1) * 8;
  const int b_off = (kg >> 1) * 4096 + (wc * 64 + fro) * 16 + (kg & 1) * 8;

  f32x4 acc[8][4] = {};

  const int NT = K / T_BK;  // 32 K-tiles, 4 phases each

  // prologue: stage slices for phases 0..3 (kt=0, kk=0..3), slots 0..3
#pragma unroll
  for (int kk = 0; kk < 4; ++kk) {
    gl_lds16(a_src + kk * 32, Ab + kk * 8192 + soff);
    gl_lds16(b_src + kk * 32, Bb + kk * 8192 + soff);
  }
  asm volatile("s_waitcnt vmcnt(6)" ::: "memory");  // phase-0 pair landed
  __builtin_amdgcn_s_barrier();

  for (int kt = 0; kt < NT; ++kt) {
    const int kt1 = (kt + 1 < NT) ? (kt + 1) : (NT - 1);  // clamped dummy tail keeps vmcnt uniform
    const uint8_t* an = a_src + (size_t)kt1 * T_BK;
    const uint8_t* bn = b_src + (size_t)kt1 * T_BK;
    const int sb = (kt & 1) * 4;   // this K-tile's slots
    const int sb2 = 4 - sb;        // next K-tile's slots
#pragma unroll
    for (int kk = 0; kk < 4; ++kk) {
      const uint8_t* Asl = Ab + (sb + kk) * 8192;
      const uint8_t* Bsl = Bb + (sb + kk) * 8192;
      long a[8], b[4];
#pragma unroll
      for (int m = 0; m < 8; ++m) a[m] = *(const long*)(Asl + a_off + m * 256);
#pragma unroll
      for (int n = 0; n < 4; ++n) b[n] = *(const long*)(Bsl + b_off + n * 256);
      // stage slice for phase g+4 (slot written last read 4 phases ago)
      gl_lds16(an + kk * 32, Ab + (sb2 + kk) * 8192 + soff);
      gl_lds16(bn + kk * 32, Bb + (sb2 + kk) * 8192 + soff);
      // counted wait: newest 3 phase-pairs may stay in flight
      asm volatile("s_waitcnt vmcnt(6)" ::: "memory");
      __builtin_amdgcn_s_barrier();
      asm volatile("s_waitcnt lgkmcnt(0)" ::: "memory");
      __builtin_amdgcn_s_setprio(1);
#pragma unroll
      for (int m = 0; m < 8; ++m)
#pragma unroll
        for (int n = 0; n < 4; ++n)
          acc[m][n] = __builtin_amdgcn_mfma_f32_16x16x32_fp8_fp8(
              a[m], b[n], acc[m][n], 0, 0, 0);
      __builtin_amdgcn_s_setprio(0);
      __builtin_amdgcn_s_barrier();
    }
  }

  // epilogue: C = acc * (x_scale*w_scale) + bias
  const float s = scales[4];
  const int crow = m0 + wr * 128 + (l >> 4) * 4;
  const int ccol = n0 + wc * 64 + (l & 15);
#pragma unroll
  for (int n = 0; n < 4; ++n) {
    const int col = ccol + n * 16;
    const float bv = bias[col];
#pragma unroll
    for (int m = 0; m < 8; ++m) {
      const int row = crow + m * 16;
#pragma unroll
      for (int r = 0; r < 4; ++r)
        C[(size_t)(row + r) * N + col] = acc[m][n][r] * s + bv;
    }
  }
}

extern "C" void kernel_launch(void* const* d_in, const int* in_sizes, int n_in,
                              void* d_out, int out_size, void* d_ws, size_t ws_size,
                              hipStream_t stream) {
  const float* inp = (const float*)d_in[0];
  const float* weight = (const float*)d_in[1];
  const float* bias = (const float*)d_in[2];
  float* out = (float*)d_out;

  const int N = in_sizes[2];                 // 16384
  const int K = in_sizes[1] / N;             // 4096
  const int M = in_sizes[0] / K;             // 8192

  uint8_t* ws = (uint8_t*)d_ws;
  float* scales = (float*)ws;
  uint8_t* xq = ws + 256;
  uint8_t* wqt = ws + 256 + (size_t)M * K;

  hipMemsetAsync(d_ws, 0, 256, stream);

  absmax_kernel<<<2048, 256, 0, stream>>>((const float4*)weight,
                                          (size_t)K * N / 4,
                                          (unsigned int*)ws + 0);
  absmax_kernel<<<2048, 256, 0, stream>>>((const float4*)inp,
                                          (size_t)M * K / 4,
                                          (unsigned int*)ws + 1);
  scales_kernel<<<1, 1, 0, stream>>>(scales);

  quantize_x_kernel<<<4096, 256, 0, stream>>>((const float4*)inp,
                                              (uint32_t*)xq, scales, M * K / 4);
  quantize_wT_kernel<<<dim3(N / 64, K / 64), 256, 0, stream>>>(weight, wqt,
                                                               scales, N, K);

  gemm_fp8_8phase<<<(M / T_BM) * (N / T_BN), 512, 131072, stream>>>(
      xq, wqt, bias, scales, out, M, N, K);
}

// Round 3
// 1107.094 us; speedup vs baseline: 2.1475x; 1.3387x over previous
//
#include <hip/hip_runtime.h>
#include <stdint.h>
#include <stddef.h>

typedef float f32x4 __attribute__((ext_vector_type(4)));

// ---------------------------------------------------------------------------
// Quantized operands are stored in "LDS-image" layout: a sequence of 8 KB
// slots. Slot s = blk*(K/32) + ksl holds rows [blk*256, blk*256+256) x
// k-bytes [ksl*32, ksl*32+32), as logical L = row*32 + kkb, stored at
// physical P = L ^ (((L>>7)&3)<<3)   (row bits 2-3 -> addr bits 3-4).
// GEMM stages a slot with a LINEAR contiguous copy (global_load_lds x16,
// 1 KiB per wave), and reads fragments at
//   P = row*32 + ((kg ^ ((fro>>2)&3))*8)
// -> bank-pair (kg^(fro>>2), fro&3) is bijective per quarter-wave: zero
// bank conflicts (4 accesses/bank = the wave64 b64 floor).
//
// Workspace layout (bytes):
//   [0..7]    : two u32 atomic absmax slots (w_absmax_bits, x_absmax_bits)
//   [8..255]  : scales: idx2=1/w_scale, idx3=1/x_scale, idx4=w_scale*x_scale
//   [256 .. 256+M*K)            : x_q  LDS-image slots (32 MB)
//   [256+M*K .. 256+M*K+N*K)    : w_qT LDS-image slots (64 MB)
// ---------------------------------------------------------------------------

__global__ void absmax_kernel(const float4* __restrict__ x, size_t n4,
                              unsigned int* __restrict__ out) {
  size_t idx = (size_t)blockIdx.x * blockDim.x + threadIdx.x;
  size_t stride = (size_t)gridDim.x * blockDim.x;
  float m = 0.f;
  for (size_t i = idx; i < n4; i += stride) {
    float4 v = x[i];
    m = fmaxf(m, fmaxf(fmaxf(fabsf(v.x), fabsf(v.y)),
                       fmaxf(fabsf(v.z), fabsf(v.w))));
  }
#pragma unroll
  for (int off = 32; off > 0; off >>= 1)
    m = fmaxf(m, __shfl_xor(m, off));
  if ((threadIdx.x & 63) == 0)
    atomicMax(out, __float_as_uint(m));  // all values >= 0: uint order == float order
}

__global__ void scales_kernel(float* __restrict__ s) {
  const unsigned int* u = (const unsigned int*)s;
  float wmax = __uint_as_float(u[0]);
  float xmax = __uint_as_float(u[1]);
  float w_scale = wmax / 448.0f;
  float x_scale = xmax / 448.0f;
  s[2] = 1.0f / w_scale;
  s[3] = 1.0f / x_scale;
  s[4] = x_scale * w_scale;
}

// x [M][K] f32 -> LDS-image slots. One thread = one 16B logical chunk.
__global__ void quantize_x_kernel(const float4* __restrict__ x,
                                  uint8_t* __restrict__ xq,
                                  const float* __restrict__ scales,
                                  int K, int n_chunks) {
  const float inv = scales[3];
  const int kslots = K >> 5;
  int idx = blockIdx.x * blockDim.x + threadIdx.x;
  const int stride = gridDim.x * blockDim.x;
  for (; idx < n_chunks; idx += stride) {
    const int slot = idx >> 9;        // 512 chunks of 16B per 8KB slot
    const int p16 = idx & 511;
    const int row = p16 >> 1;
    const int kkb0 = (p16 & 1) << 4;
    const int mblk = slot / kslots;
    const int ksl = slot - mblk * kslots;
    const size_t f4 = ((size_t)(mblk * 256 + row) * K + ksl * 32 + kkb0) >> 2;
    const float4 v0 = x[f4 + 0], v1 = x[f4 + 1], v2 = x[f4 + 2], v3 = x[f4 + 3];
    uint32_t c0 = __builtin_amdgcn_cvt_pk_fp8_f32(v0.x * inv, v0.y * inv, 0, false);
    c0 = __builtin_amdgcn_cvt_pk_fp8_f32(v0.z * inv, v0.w * inv, c0, true);
    uint32_t c1 = __builtin_amdgcn_cvt_pk_fp8_f32(v1.x * inv, v1.y * inv, 0, false);
    c1 = __builtin_amdgcn_cvt_pk_fp8_f32(v1.z * inv, v1.w * inv, c1, true);
    uint32_t c2 = __builtin_amdgcn_cvt_pk_fp8_f32(v2.x * inv, v2.y * inv, 0, false);
    c2 = __builtin_amdgcn_cvt_pk_fp8_f32(v2.z * inv, v2.w * inv, c2, true);
    uint32_t c3 = __builtin_amdgcn_cvt_pk_fp8_f32(v3.x * inv, v3.y * inv, 0, false);
    c3 = __builtin_amdgcn_cvt_pk_fp8_f32(v3.z * inv, v3.w * inv, c3, true);
    const unsigned long long L0 = (unsigned long long)c0 | ((unsigned long long)c1 << 32);
    const unsigned long long L1 = (unsigned long long)c2 | ((unsigned long long)c3 << 32);
    const int Lc = row * 32 + kkb0;
    const int mask = ((row >> 2) & 3) << 3;
    const int addr0 = Lc ^ (mask & 16);
    uint8_t* p = xq + (size_t)slot * 8192;
    *(unsigned long long*)(p + addr0 + (mask & 8)) = L0;
    *(unsigned long long*)(p + addr0 + (8 ^ (mask & 8))) = L1;
  }
}

// w [K][N] f32 -> w^T LDS-image slots (row = n, 256-row blocks).
// 64x64 tile transpose per block; grid = (N/64, K/64), 256 threads.
__global__ void quantize_wT_kernel(const float* __restrict__ w,
                                   uint8_t* __restrict__ wqt,
                                   const float* __restrict__ scales,
                                   int N, int K) {
  __shared__ uint8_t tile[64][68];  // [k][n], padded
  const float inv = scales[2];
  const int tn = blockIdx.x;
  const int tk = blockIdx.y;
  const int t = threadIdx.x;
  {
    const int rr = t >> 4;   // 0..15
    const int cc4 = t & 15;  // float4 column
#pragma unroll
    for (int i = 0; i < 4; ++i) {
      const int row = rr + i * 16;  // k within tile
      const float4 v = *(const float4*)&w[(size_t)(tk * 64 + row) * N + tn * 64 + cc4 * 4];
      uint32_t c = __builtin_amdgcn_cvt_pk_fp8_f32(v.x * inv, v.y * inv, 0, false);
      c = __builtin_amdgcn_cvt_pk_fp8_f32(v.z * inv, v.w * inv, c, true);
      *(uint32_t*)&tile[row][cc4 * 4] = c;
    }
  }
  __syncthreads();
  {
    const int nrow = t & 63;      // n within tile
    const int kc16 = t >> 6;      // which 16B k-chunk (0..3)
    unsigned long long L0 = 0, L1 = 0;
#pragma unroll
    for (int j = 0; j < 8; ++j)
      L0 |= (unsigned long long)tile[kc16 * 16 + j][nrow] << (8 * j);
#pragma unroll
    for (int j = 0; j < 8; ++j)
      L1 |= (unsigned long long)tile[kc16 * 16 + 8 + j][nrow] << (8 * j);
    const int n_g = tn * 64 + nrow;
    const int k0g = tk * 64 + kc16 * 16;
    const size_t slot = (size_t)(n_g >> 8) * (K >> 5) + (k0g >> 5);
    const int row = n_g & 255;
    const int kkb0 = k0g & 31;
    const int Lc = row * 32 + kkb0;
    const int mask = ((row >> 2) & 3) << 3;
    const int addr0 = Lc ^ (mask & 16);
    uint8_t* p = wqt + slot * 8192;
    *(unsigned long long*)(p + addr0 + (mask & 8)) = L0;
    *(unsigned long long*)(p + addr0 + (8 ^ (mask & 8))) = L1;
  }
}

// ---------------------------------------------------------------------------
// fp8 GEMM, 256x256 tile, 8-phase ring schedule (T3+T4+T5), swizzled slots.
// ---------------------------------------------------------------------------
#define T_BM 256
#define T_BN 256
#define T_BK 128

__device__ __forceinline__ void gl_lds16(const uint8_t* g, uint8_t* lds) {
  __builtin_amdgcn_global_load_lds(
      (const __attribute__((address_space(1))) void*)g,
      (__attribute__((address_space(3))) void*)lds, 16, 0, 0);
}

__global__ __launch_bounds__(512, 2) void gemm_fp8_8phase(
    const uint8_t* __restrict__ Aq, const uint8_t* __restrict__ BqT,
    const float* __restrict__ bias, const float* __restrict__ scales,
    float* __restrict__ C, int M, int N, int K) {
  extern __shared__ uint8_t smem[];
  uint8_t* const Ab = smem;            // 8 slots x 8192 = 64 KB
  uint8_t* const Bb = smem + 65536;    // 8 slots x 8192 = 64 KB

  const int ntn = N / T_BN;
  const int bid = blockIdx.x;
  const int m0 = (bid / ntn) * T_BM;
  const int n0 = (bid % ntn) * T_BN;

  const int tid = threadIdx.x;
  const int w = tid >> 6;      // wave 0..7
  const int l = tid & 63;
  const int wr = w >> 2;       // 0..1  (M half)
  const int wc = w & 3;        // 0..3  (N quarter)

  const int kslots = K >> 5;   // 32-k-byte slices per row-block

  // staging: linear contiguous copy of one 8KB slot; wave w owns bytes
  // [w*1024, w*1024+1024), lane l the 16B at +l*16.
  const int soff = w * 1024 + l * 16;
  const uint8_t* a_src = Aq + (size_t)(m0 >> 8) * kslots * 8192 + soff;
  const uint8_t* b_src = BqT + (size_t)(n0 >> 8) * kslots * 8192 + soff;

  // fragment-read offsets (swizzle folded into the per-lane constant)
  const int fro = l & 15;
  const int kg = l >> 4;
  const int fmask = ((fro >> 2) & 3) << 3;
  const int a_off = (((wr * 128 + fro) * 32) + kg * 8) ^ fmask;
  const int b_off = (((wc * 64 + fro) * 32) + kg * 8) ^ fmask;

  f32x4 acc[8][4] = {};

  const int NT = K / T_BK;  // K-tiles of 128 k-bytes = 4 slices each

  // prologue: stage slices 0..3 into slots 0..3
#pragma unroll
  for (int kk = 0; kk < 4; ++kk) {
    gl_lds16(a_src + (size_t)kk * 8192, Ab + kk * 8192 + soff);
    gl_lds16(b_src + (size_t)kk * 8192, Bb + kk * 8192 + soff);
  }
  asm volatile("s_waitcnt vmcnt(6)" ::: "memory");  // phase-0 pair landed
  __builtin_amdgcn_s_barrier();

  for (int kt = 0; kt < NT; ++kt) {
    const int kt1 = (kt + 1 < NT) ? (kt + 1) : (NT - 1);  // clamped dummy tail
    const uint8_t* an = a_src + (size_t)kt1 * 4 * 8192;
    const uint8_t* bn = b_src + (size_t)kt1 * 4 * 8192;
    const int sb = (kt & 1) * 4;   // this K-tile's slots
    const int sb2 = 4 - sb;        // next K-tile's slots
#pragma unroll
    for (int kk = 0; kk < 4; ++kk) {
      const uint8_t* Asl = Ab + (sb + kk) * 8192;
      const uint8_t* Bsl = Bb + (sb + kk) * 8192;
      long a[8], b[4];
#pragma unroll
      for (int m = 0; m < 8; ++m) a[m] = *(const long*)(Asl + a_off + m * 512);
#pragma unroll
      for (int n = 0; n < 4; ++n) b[n] = *(const long*)(Bsl + b_off + n * 512);
      // stage slice for phase g+4 (ring lead 4)
      gl_lds16(an + (size_t)kk * 8192, Ab + (sb2 + kk) * 8192 + soff);
      gl_lds16(bn + (size_t)kk * 8192, Bb + (sb2 + kk) * 8192 + soff);
      // counted wait: newest 3 phase-pairs stay in flight
      asm volatile("s_waitcnt vmcnt(6)" ::: "memory");
      __builtin_amdgcn_s_barrier();
      asm volatile("s_waitcnt lgkmcnt(0)" ::: "memory");
      __builtin_amdgcn_s_setprio(1);
#pragma unroll
      for (int m = 0; m < 8; ++m)
#pragma unroll
        for (int n = 0; n < 4; ++n)
          acc[m][n] = __builtin_amdgcn_mfma_f32_16x16x32_fp8_fp8(
              a[m], b[n], acc[m][n], 0, 0, 0);
      __builtin_amdgcn_s_setprio(0);
      __builtin_amdgcn_s_barrier();
    }
  }

  // epilogue: C = acc * (x_scale*w_scale) + bias
  const float s = scales[4];
  const int crow = m0 + wr * 128 + (l >> 4) * 4;
  const int ccol = n0 + wc * 64 + (l & 15);
#pragma unroll
  for (int n = 0; n < 4; ++n) {
    const int col = ccol + n * 16;
    const float bv = bias[col];
#pragma unroll
    for (int m = 0; m < 8; ++m) {
      const int row = crow + m * 16;
#pragma unroll
      for (int r = 0; r < 4; ++r)
        C[(size_t)(row + r) * N + col] = acc[m][n][r] * s + bv;
    }
  }
}

extern "C" void kernel_launch(void* const* d_in, const int* in_sizes, int n_in,
                              void* d_out, int out_size, void* d_ws, size_t ws_size,
                              hipStream_t stream) {
  const float* inp = (const float*)d_in[0];
  const float* weight = (const float*)d_in[1];
  const float* bias = (const float*)d_in[2];
  float* out = (float*)d_out;

  const int N = in_sizes[2];                 // 16384
  const int K = in_sizes[1] / N;             // 4096
  const int M = in_sizes[0] / K;             // 8192

  uint8_t* ws = (uint8_t*)d_ws;
  float* scales = (float*)ws;
  uint8_t* xq = ws + 256;
  uint8_t* wqt = ws + 256 + (size_t)M * K;

  hipMemsetAsync(d_ws, 0, 256, stream);

  absmax_kernel<<<2048, 256, 0, stream>>>((const float4*)weight,
                                          (size_t)K * N / 4,
                                          (unsigned int*)ws + 0);
  absmax_kernel<<<2048, 256, 0, stream>>>((const float4*)inp,
                                          (size_t)M * K / 4,
                                          (unsigned int*)ws + 1);
  scales_kernel<<<1, 1, 0, stream>>>(scales);

  quantize_x_kernel<<<4096, 256, 0, stream>>>((const float4*)inp, xq, scales,
                                              K, M * K / 16);
  quantize_wT_kernel<<<dim3(N / 64, K / 64), 256, 0, stream>>>(weight, wqt,
                                                               scales, N, K);

  gemm_fp8_8phase<<<(M / T_BM) * (N / T_BN), 512, 131072, stream>>>(
      xq, wqt, bias, scales, out, M, N, K);
}

// Round 4
// 935.174 us; speedup vs baseline: 2.5422x; 1.1838x over previous
//
#include <hip/hip_runtime.h>
#include <stdint.h>
#include <stddef.h>

typedef float f32x4 __attribute__((ext_vector_type(4)));
typedef int i32x8 __attribute__((ext_vector_type(8)));

union Frag32 { long l[4]; i32x8 v; };  // 32 bytes = one scaled-MFMA operand/lane

// ---------------------------------------------------------------------------
// Quantized operands live in an "LDS-image" layout: 8 KB slots; slot
// s = blk*(K/32) + ksl holds rows [blk*256..+256) x k-bytes [ksl*32..+32),
// logical L = row*32 + kkb stored at P = L ^ (((L>>7)&3)<<3).
// GEMM stages a slot with a LINEAR contiguous copy (global_load_lds x16);
// fragment ds_read_b64 at P = row*32 + ((j ^ ((row>>2)&3))*8) hits a
// bijective bank-pair pattern: zero conflicts (verified R3: SQ_LDS_BANK_CONFLICT=0).
//
// GEMM inner op: mfma_scale_f32_16x16x128_f8f6f4 with unit E8M0 scales
// (0x7F per byte -> x1.0): bit-exact fp8 matmul at the 2x MX rate.
// Lane's 32-byte fragment = its quarter's slice q = lane>>4 -> one slot row.
//
// Workspace layout (bytes):
//   [0..7]    : two u32 atomic absmax slots (w_absmax_bits, x_absmax_bits)
//   [8..255]  : scales: idx2=1/w_scale, idx3=1/x_scale, idx4=w_scale*x_scale
//   [256 .. 256+M*K)            : x_q  LDS-image slots (32 MB)
//   [256+M*K .. 256+M*K+N*K)    : w_qT LDS-image slots (64 MB)
// ---------------------------------------------------------------------------

__global__ void absmax_kernel(const float4* __restrict__ x, size_t n4,
                              unsigned int* __restrict__ out) {
  size_t idx = (size_t)blockIdx.x * blockDim.x + threadIdx.x;
  size_t stride = (size_t)gridDim.x * blockDim.x;
  float m = 0.f;
  for (size_t i = idx; i < n4; i += stride) {
    float4 v = x[i];
    m = fmaxf(m, fmaxf(fmaxf(fabsf(v.x), fabsf(v.y)),
                       fmaxf(fabsf(v.z), fabsf(v.w))));
  }
#pragma unroll
  for (int off = 32; off > 0; off >>= 1)
    m = fmaxf(m, __shfl_xor(m, off));
  if ((threadIdx.x & 63) == 0)
    atomicMax(out, __float_as_uint(m));  // all values >= 0: uint order == float order
}

__global__ void scales_kernel(float* __restrict__ s) {
  const unsigned int* u = (const unsigned int*)s;
  float wmax = __uint_as_float(u[0]);
  float xmax = __uint_as_float(u[1]);
  float w_scale = wmax / 448.0f;
  float x_scale = xmax / 448.0f;
  s[2] = 1.0f / w_scale;
  s[3] = 1.0f / x_scale;
  s[4] = x_scale * w_scale;
}

// x [M][K] f32 -> LDS-image slots. One thread = one 16B logical chunk.
__global__ void quantize_x_kernel(const float4* __restrict__ x,
                                  uint8_t* __restrict__ xq,
                                  const float* __restrict__ scales,
                                  int K, int n_chunks) {
  const float inv = scales[3];
  const int kslots = K >> 5;
  int idx = blockIdx.x * blockDim.x + threadIdx.x;
  const int stride = gridDim.x * blockDim.x;
  for (; idx < n_chunks; idx += stride) {
    const int slot = idx >> 9;        // 512 chunks of 16B per 8KB slot
    const int p16 = idx & 511;
    const int row = p16 >> 1;
    const int kkb0 = (p16 & 1) << 4;
    const int mblk = slot / kslots;
    const int ksl = slot - mblk * kslots;
    const size_t f4 = ((size_t)(mblk * 256 + row) * K + ksl * 32 + kkb0) >> 2;
    const float4 v0 = x[f4 + 0], v1 = x[f4 + 1], v2 = x[f4 + 2], v3 = x[f4 + 3];
    uint32_t c0 = __builtin_amdgcn_cvt_pk_fp8_f32(v0.x * inv, v0.y * inv, 0, false);
    c0 = __builtin_amdgcn_cvt_pk_fp8_f32(v0.z * inv, v0.w * inv, c0, true);
    uint32_t c1 = __builtin_amdgcn_cvt_pk_fp8_f32(v1.x * inv, v1.y * inv, 0, false);
    c1 = __builtin_amdgcn_cvt_pk_fp8_f32(v1.z * inv, v1.w * inv, c1, true);
    uint32_t c2 = __builtin_amdgcn_cvt_pk_fp8_f32(v2.x * inv, v2.y * inv, 0, false);
    c2 = __builtin_amdgcn_cvt_pk_fp8_f32(v2.z * inv, v2.w * inv, c2, true);
    uint32_t c3 = __builtin_amdgcn_cvt_pk_fp8_f32(v3.x * inv, v3.y * inv, 0, false);
    c3 = __builtin_amdgcn_cvt_pk_fp8_f32(v3.z * inv, v3.w * inv, c3, true);
    const unsigned long long L0 = (unsigned long long)c0 | ((unsigned long long)c1 << 32);
    const unsigned long long L1 = (unsigned long long)c2 | ((unsigned long long)c3 << 32);
    const int Lc = row * 32 + kkb0;
    const int mask = ((row >> 2) & 3) << 3;
    const int addr0 = Lc ^ (mask & 16);
    uint8_t* p = xq + (size_t)slot * 8192;
    *(unsigned long long*)(p + addr0 + (mask & 8)) = L0;
    *(unsigned long long*)(p + addr0 + (8 ^ (mask & 8))) = L1;
  }
}

// w [K][N] f32 -> w^T LDS-image slots (row = n, 256-row blocks).
__global__ void quantize_wT_kernel(const float* __restrict__ w,
                                   uint8_t* __restrict__ wqt,
                                   const float* __restrict__ scales,
                                   int N, int K) {
  __shared__ uint8_t tile[64][68];  // [k][n], padded
  const float inv = scales[2];
  const int tn = blockIdx.x;
  const int tk = blockIdx.y;
  const int t = threadIdx.x;
  {
    const int rr = t >> 4;
    const int cc4 = t & 15;
#pragma unroll
    for (int i = 0; i < 4; ++i) {
      const int row = rr + i * 16;  // k within tile
      const float4 v = *(const float4*)&w[(size_t)(tk * 64 + row) * N + tn * 64 + cc4 * 4];
      uint32_t c = __builtin_amdgcn_cvt_pk_fp8_f32(v.x * inv, v.y * inv, 0, false);
      c = __builtin_amdgcn_cvt_pk_fp8_f32(v.z * inv, v.w * inv, c, true);
      *(uint32_t*)&tile[row][cc4 * 4] = c;
    }
  }
  __syncthreads();
  {
    const int nrow = t & 63;
    const int kc16 = t >> 6;
    unsigned long long L0 = 0, L1 = 0;
#pragma unroll
    for (int j = 0; j < 8; ++j)
      L0 |= (unsigned long long)tile[kc16 * 16 + j][nrow] << (8 * j);
#pragma unroll
    for (int j = 0; j < 8; ++j)
      L1 |= (unsigned long long)tile[kc16 * 16 + 8 + j][nrow] << (8 * j);
    const int n_g = tn * 64 + nrow;
    const int k0g = tk * 64 + kc16 * 16;
    const size_t slot = (size_t)(n_g >> 8) * (K >> 5) + (k0g >> 5);
    const int row = n_g & 255;
    const int kkb0 = k0g & 31;
    const int Lc = row * 32 + kkb0;
    const int mask = ((row >> 2) & 3) << 3;
    const int addr0 = Lc ^ (mask & 16);
    uint8_t* p = wqt + slot * 8192;
    *(unsigned long long*)(p + addr0 + (mask & 8)) = L0;
    *(unsigned long long*)(p + addr0 + (8 ^ (mask & 8))) = L1;
  }
}

// ---------------------------------------------------------------------------
// fp8 GEMM, 256x256 tile, per-K-tile phases, MX-scaled 16x16x128 MFMA.
// ---------------------------------------------------------------------------
#define T_BM 256
#define T_BN 256
#define T_BK 128
#define UNIT_SCALE 0x7F7F7F7F

__device__ __forceinline__ void gl_lds16(const uint8_t* g, uint8_t* lds) {
  __builtin_amdgcn_global_load_lds(
      (const __attribute__((address_space(1))) void*)g,
      (__attribute__((address_space(3))) void*)lds, 16, 0, 0);
}

__global__ __launch_bounds__(512, 2) void gemm_fp8_mx(
    const uint8_t* __restrict__ Aq, const uint8_t* __restrict__ BqT,
    const float* __restrict__ bias, const float* __restrict__ scales,
    float* __restrict__ C, int M, int N, int K) {
  extern __shared__ uint8_t smem[];
  uint8_t* const Ab = smem;            // 8 slots x 8192 = 64 KB
  uint8_t* const Bb = smem + 65536;    // 8 slots x 8192 = 64 KB

  const int ntn = N / T_BN;
  const int bid = blockIdx.x;
  const int m0 = (bid / ntn) * T_BM;
  const int n0 = (bid % ntn) * T_BN;

  const int tid = threadIdx.x;
  const int w = tid >> 6;      // wave 0..7
  const int l = tid & 63;
  const int wr = w >> 2;       // 0..1  (M half)
  const int wc = w & 3;        // 0..3  (N quarter)

  const int kslots = K >> 5;

  // staging: linear contiguous copy of one 8KB slot; wave w owns bytes
  // [w*1024, w*1024+1024), lane l the 16B at +l*16.
  const int soff = w * 1024 + l * 16;
  const uint8_t* a_src = Aq + (size_t)(m0 >> 8) * kslots * 8192 + soff;
  const uint8_t* b_src = BqT + (size_t)(n0 >> 8) * kslots * 8192 + soff;

  // fragment-read constants: lane's quarter q reads slice/slot q only.
  const int fro = l & 15;
  const int kq = l >> 4;
  const int fswz = ((fro >> 2) & 3) << 3;
  int aoff[4], boff[4];
#pragma unroll
  for (int j = 0; j < 4; ++j) {
    const int js = (j * 8) ^ fswz;
    aoff[j] = (wr * 128 + fro) * 32 + js;
    boff[j] = (wc * 64 + fro) * 32 + js;
  }

  f32x4 acc[8][4] = {};

  const int NT = K / T_BK;  // 32 K-tiles

  // prologue: stage K-tile 0 into slots 0..3
#pragma unroll
  for (int kk = 0; kk < 4; ++kk) {
    gl_lds16(a_src + (size_t)kk * 8192, Ab + kk * 8192 + soff);
    gl_lds16(b_src + (size_t)kk * 8192, Bb + kk * 8192 + soff);
  }
  asm volatile("s_waitcnt vmcnt(0)" ::: "memory");
  __builtin_amdgcn_s_barrier();

  for (int kt = 0; kt < NT; ++kt) {
    const int kt1 = (kt + 1 < NT) ? (kt + 1) : (NT - 1);  // clamped dummy tail
    const uint8_t* an = a_src + (size_t)kt1 * 4 * 8192;
    const uint8_t* bn = b_src + (size_t)kt1 * 4 * 8192;
    const int sb = (kt & 1) * 4;   // this K-tile's slots
    const int sb2 = 4 - sb;        // next K-tile's slots
    const uint8_t* Aslot = Ab + (sb + kq) * 8192;
    const uint8_t* Bslot = Bb + (sb + kq) * 8192;

    Frag32 b4[4], a4[4];
#pragma unroll
    for (int n = 0; n < 4; ++n)
#pragma unroll
      for (int j = 0; j < 4; ++j)
        b4[n].l[j] = *(const long*)(Bslot + boff[j] + n * 512);
#pragma unroll
    for (int m = 0; m < 4; ++m)
#pragma unroll
      for (int j = 0; j < 4; ++j)
        a4[m].l[j] = *(const long*)(Aslot + aoff[j] + m * 512);

    // stage K-tile kt+1 (flight time = rest of this phase's MFMA cluster)
#pragma unroll
    for (int kk = 0; kk < 4; ++kk) {
      gl_lds16(an + (size_t)kk * 8192, Ab + (sb2 + kk) * 8192 + soff);
      gl_lds16(bn + (size_t)kk * 8192, Bb + (sb2 + kk) * 8192 + soff);
    }

    asm volatile("s_waitcnt lgkmcnt(0)" ::: "memory");
    __builtin_amdgcn_s_setprio(1);
#pragma unroll
    for (int m = 0; m < 4; ++m)
#pragma unroll
      for (int n = 0; n < 4; ++n)
        acc[m][n] = __builtin_amdgcn_mfma_scale_f32_16x16x128_f8f6f4(
            a4[m].v, b4[n].v, acc[m][n], 0, 0, 0, UNIT_SCALE, 0, UNIT_SCALE);
    __builtin_amdgcn_s_setprio(0);

    Frag32 a8[4];
#pragma unroll
    for (int m = 0; m < 4; ++m)
#pragma unroll
      for (int j = 0; j < 4; ++j)
        a8[m].l[j] = *(const long*)(Aslot + aoff[j] + (m + 4) * 512);

    asm volatile("s_waitcnt lgkmcnt(0)" ::: "memory");
    __builtin_amdgcn_s_setprio(1);
#pragma unroll
    for (int m = 0; m < 4; ++m)
#pragma unroll
      for (int n = 0; n < 4; ++n)
        acc[m + 4][n] = __builtin_amdgcn_mfma_scale_f32_16x16x128_f8f6f4(
            a8[m].v, b4[n].v, acc[m + 4][n], 0, 0, 0, UNIT_SCALE, 0, UNIT_SCALE);
    __builtin_amdgcn_s_setprio(0);

    // kt+1's loads have had the whole MFMA cluster to fly
    asm volatile("s_waitcnt vmcnt(0)" ::: "memory");
    __builtin_amdgcn_s_barrier();
  }

  // epilogue: C = acc * (x_scale*w_scale) + bias
  const float s = scales[4];
  const int crow = m0 + wr * 128 + (l >> 4) * 4;
  const int ccol = n0 + wc * 64 + (l & 15);
#pragma unroll
  for (int n = 0; n < 4; ++n) {
    const int col = ccol + n * 16;
    const float bv = bias[col];
#pragma unroll
    for (int m = 0; m < 8; ++m) {
      const int row = crow + m * 16;
#pragma unroll
      for (int r = 0; r < 4; ++r)
        C[(size_t)(row + r) * N + col] = acc[m][n][r] * s + bv;
    }
  }
}

extern "C" void kernel_launch(void* const* d_in, const int* in_sizes, int n_in,
                              void* d_out, int out_size, void* d_ws, size_t ws_size,
                              hipStream_t stream) {
  const float* inp = (const float*)d_in[0];
  const float* weight = (const float*)d_in[1];
  const float* bias = (const float*)d_in[2];
  float* out = (float*)d_out;

  const int N = in_sizes[2];                 // 16384
  const int K = in_sizes[1] / N;             // 4096
  const int M = in_sizes[0] / K;             // 8192

  uint8_t* ws = (uint8_t*)d_ws;
  float* scales = (float*)ws;
  uint8_t* xq = ws + 256;
  uint8_t* wqt = ws + 256 + (size_t)M * K;

  hipMemsetAsync(d_ws, 0, 256, stream);

  absmax_kernel<<<2048, 256, 0, stream>>>((const float4*)weight,
                                          (size_t)K * N / 4,
                                          (unsigned int*)ws + 0);
  absmax_kernel<<<2048, 256, 0, stream>>>((const float4*)inp,
                                          (size_t)M * K / 4,
                                          (unsigned int*)ws + 1);
  scales_kernel<<<1, 1, 0, stream>>>(scales);

  quantize_x_kernel<<<4096, 256, 0, stream>>>((const float4*)inp, xq, scales,
                                              K, M * K / 16);
  quantize_wT_kernel<<<dim3(N / 64, K / 64), 256, 0, stream>>>(weight, wqt,
                                                               scales, N, K);

  gemm_fp8_mx<<<(M / T_BM) * (N / T_BN), 512, 131072, stream>>>(
      xq, wqt, bias, scales, out, M, N, K);
}